// Round 1
// baseline (422.674 us; speedup 1.0000x reference)
//
#include <hip/hip_runtime.h>
#include <math.h>

#define BB 64
#define TT 256
#define KK 32
#define VV 32
#define CH 64                 // chunk rows per block
#define PH 32                 // steps per phase
#define ROWS (CH + PH)        // 96 rows staged (chunk + halo)
#define NPHASE ((TT + KK) / PH)  // 9 phases * 32 = 288 steps
#define BPB (TT / CH)         // 4 blocks per batch

// workspace layout (floats)
#define RW_OFF    0                       // K*K = 1024
#define WOP_OFF   1024                    // 37*K = 1184 (rows: 5 op weights then 32 atom rows)
#define ATOM_OFF  2240                    // B*T*K
#define STATE_OFF (ATOM_OFF + BB*TT*KK)   // B*T*K

__device__ __forceinline__ float myrelu(float z) {
    float r = 0.01f * z;
    return (z < 0.f) ? r : (z > 1.f ? r + 0.99f : z);
}

// --- tiny: softmaxes of w_op (32 rows x 37) and w_right (32 rows x 33) ---
__global__ void prep_kernel(const float* __restrict__ w_right,
                            const float* __restrict__ w_op,
                            float* __restrict__ ws) {
    int tid = threadIdx.x;
    float* rw  = ws + RW_OFF;   // rw[k*K + j] = right_w[k][j] = softmax(w_right)[j][k]
    float* wop = ws + WOP_OFF;  // wop[i*K + k] = sm_op[k][i]   (i = 0..36)
    if (tid < KK) {
        float v[37];
        float m = -1e30f;
        #pragma unroll
        for (int i = 0; i < 37; ++i) { v[i] = w_op[tid * 37 + i]; m = fmaxf(m, v[i]); }
        float s = 0.f;
        #pragma unroll
        for (int i = 0; i < 37; ++i) { v[i] = expf(v[i] - m); s += v[i]; }
        float inv = 1.f / s;
        #pragma unroll
        for (int i = 0; i < 37; ++i) wop[i * KK + tid] = v[i] * inv;
    } else if (tid < 2 * KK) {
        int r = tid - KK;   // row of w_right
        float v[KK + 1];
        float m = -1e30f;
        #pragma unroll
        for (int i = 0; i <= KK; ++i) { v[i] = w_right[r * (KK + 1) + i]; m = fmaxf(m, v[i]); }
        float s = 0.f;
        #pragma unroll
        for (int i = 0; i <= KK; ++i) { v[i] = expf(v[i] - m); s += v[i]; }
        float inv = 1.f / s;
        // softmax(w_right)[r][c] == right_w[c][r]  -> rw[c*K + r]
        #pragma unroll
        for (int c = 0; c < KK; ++c) rw[c * KK + r] = v[c] * inv;
    }
}

// --- atom_x = x @ atom_w  (and zero the state buffer) ---
__global__ void atomx_kernel(const float* __restrict__ x, float* __restrict__ ws) {
    const float* aw = ws + WOP_OFF + 5 * KK;  // aw[v*K + k] = sm_op[k][5+v]
    float* atom  = ws + ATOM_OFF;
    float* state = ws + STATE_OFF;
    int tid = threadIdx.x;
    int k  = tid & (KK - 1);
    int bt = blockIdx.x * 8 + (tid >> 5);
    const float* xrow = x + bt * VV;
    float acc = 0.f;
    #pragma unroll
    for (int v = 0; v < VV; ++v) acc = fmaf(xrow[v], aw[v * KK + k], acc);
    atom[bt * KK + k]  = acc;
    state[bt * KK + k] = 0.f;
}

// --- one phase: load chunk+halo to LDS, run PH local steps, write chunk back ---
__global__ __launch_bounds__(512, 1)
void phase_kernel(float* __restrict__ ws) {
    __shared__ float Xs[2][ROWS][KK];   // 24.0 KiB double-buffered state
    __shared__ float As[ROWS][KK];      // 12.0 KiB atom_x slice
    __shared__ float Rw[KK * KK];       //  4.0 KiB
    __shared__ float Wv[4 * KK];        //  0.5 KiB (op_w rows 1..4)

    const float* rw    = ws + RW_OFF;
    const float* wop   = ws + WOP_OFF;
    const float* atom  = ws + ATOM_OFF;
    float*       state = ws + STATE_OFF;

    int tid = threadIdx.x;
    int b  = blockIdx.x / BPB;
    int c  = blockIdx.x % BPB;
    int lo = c * CH;

    for (int i = tid; i < KK * KK; i += 512) Rw[i] = rw[i];
    for (int i = tid; i < 4 * KK;  i += 512) Wv[i] = wop[KK + i];  // rows 1..4

    const float* gs = state + (size_t)(b * TT + lo) * KK;
    const float* ga = atom  + (size_t)(b * TT + lo) * KK;
    float* xs0 = &Xs[0][0][0];
    float* xs1 = &Xs[1][0][0];
    float* as0 = &As[0][0];
    for (int i = tid; i < ROWS * KK; i += 512) {
        int gt = lo + (i >> 5);
        bool ok = gt < TT;
        xs0[i] = ok ? gs[i] : 0.f;
        as0[i] = ok ? ga[i] : 0.f;
        if (!ok) xs1[i] = 0.f;   // rows >= T must read as 0 from both buffers
    }
    __syncthreads();

    int g = tid >> 5;        // 16 row-groups
    int j = tid & 31;        // k-lane
    float rwcol[KK];
    #pragma unroll
    for (int k = 0; k < KK; ++k) rwcol[k] = Rw[k * KK + j];
    float w1 = Wv[0 * KK + j], w2 = Wv[1 * KK + j], w3 = Wv[2 * KK + j], w4 = Wv[3 * KK + j];
    float av[6];
    #pragma unroll
    for (int i = 0; i < 6; ++i) av[i] = As[g + 16 * i][j];

    int cur = 0;
    for (int s = 0; s < PH; ++s) {
        const float (*X)[KK] = Xs[cur];
        float (*Y)[KK] = Xs[cur ^ 1];
        int top = lo + ROWS - 1 - s;       // exclusive global top of newly-valid rows
        if (top > TT) top = TT;
        #pragma unroll
        for (int i = 0; i < 6; ++i) {
            int r = g + 16 * i;            // local row
            int t = lo + r;                // global row
            if (t < top) {
                float a0 = 0.f, a1 = 0.f, a2 = 0.f, a3 = 0.f;
                #pragma unroll
                for (int q = 0; q < 8; ++q) {
                    float4 xv = *reinterpret_cast<const float4*>(&X[r][q * 4]);
                    a0 = fmaf(xv.x, rwcol[q * 4 + 0], a0);
                    a1 = fmaf(xv.y, rwcol[q * 4 + 1], a1);
                    a2 = fmaf(xv.z, rwcol[q * 4 + 2], a2);
                    a3 = fmaf(xv.w, rwcol[q * 4 + 3], a3);
                }
                float right = (a0 + a1) + (a2 + a3);
                float left = (j < KK - 1) ? X[r][j + 1] : 0.f;
                float nx   = X[r + 1][j];
                float xl   = (j < KK - 1) ? X[r + 1][j + 1] : 0.f;
                float until = right + myrelu(left + nx - 1.f);
                float z = av[i] + (1.f - left) * w1 + (left + right - 1.f) * w2
                        + xl * w3 + until * w4;
                Y[r][j] = myrelu(z);
            }
        }
        __syncthreads();
        cur ^= 1;
    }

    float* gso = state + (size_t)(b * TT + lo) * KK;
    const float* xsf = &Xs[cur][0][0];
    for (int i = tid; i < CH * KK; i += 512) gso[i] = xsf[i];
}

__global__ void final_kernel(const float* __restrict__ st, float* __restrict__ out) {
    int i = blockIdx.x * 256 + threadIdx.x;
    float v = st[i];
    out[i] = 1.f / (1.f + expf(-5.f * (v - 0.5f)));
}

extern "C" void kernel_launch(void* const* d_in, const int* in_sizes, int n_in,
                              void* d_out, int out_size, void* d_ws, size_t ws_size,
                              hipStream_t stream) {
    const float* x       = (const float*)d_in[0];
    const float* w_right = (const float*)d_in[1];
    const float* w_op    = (const float*)d_in[2];
    float* ws  = (float*)d_ws;
    float* out = (float*)d_out;

    prep_kernel<<<1, 64, 0, stream>>>(w_right, w_op, ws);
    atomx_kernel<<<BB * TT / 8, 256, 0, stream>>>(x, ws);
    for (int p = 0; p < NPHASE; ++p)
        phase_kernel<<<BB * BPB, 512, 0, stream>>>(ws);
    final_kernel<<<BB * TT * KK / 256, 256, 0, stream>>>(ws + STATE_OFF, out);
}

// Round 2
// 244.357 us; speedup vs baseline: 1.7297x; 1.7297x over previous
//
#include <hip/hip_runtime.h>
#include <math.h>

#define BB 64
#define TT 256
#define KK 32
#define VV 32
#define CH 64                 // chunk rows per block
#define PH 32                 // steps per phase
#define ROWS (CH + PH)        // 96 rows staged (chunk + halo)
#define NPHASE ((TT + KK) / PH)  // 9 phases * 32 = 288 steps
#define BPB (TT / CH)         // 4 blocks per batch

#define XFS 36   // Xf row stride (floats): 144 B, 16B-aligned rows
#define XBS 40   // Xb row stride (ushorts): 80 B, 16B-aligned rows

// workspace layout (floats)
#define RW_OFF    0                       // K*K
#define WOP_OFF   1024                    // 37*K
#define ATOM_OFF  2240                    // B*T*K
#define STATE_OFF (ATOM_OFF + BB*TT*KK)   // B*T*K

typedef __attribute__((ext_vector_type(8))) short short8;
typedef __attribute__((ext_vector_type(4))) float floatx4;

__device__ __forceinline__ float myrelu(float z) {
    float r = 0.01f * z;
    return (z < 0.f) ? r : (z > 1.f ? r + 0.99f : z);
}
__device__ __forceinline__ ushort f2bf(float f) {
    union { float f; unsigned int u; } v; v.f = f;
    unsigned int r = v.u + 0x7fffu + ((v.u >> 16) & 1u);
    return (ushort)(r >> 16);
}

// --- softmaxes of w_op (32 x 37) and w_right (32 x 33) ---
__global__ void prep_kernel(const float* __restrict__ w_right,
                            const float* __restrict__ w_op,
                            float* __restrict__ ws) {
    int tid = threadIdx.x;
    float* rw  = ws + RW_OFF;   // rw[k*K + j] = right_w[k][j] = softmax(w_right)[j][k]
    float* wop = ws + WOP_OFF;  // wop[i*K + k] = sm_op[k][i]
    if (tid < KK) {
        float v[37];
        float m = -1e30f;
        #pragma unroll
        for (int i = 0; i < 37; ++i) { v[i] = w_op[tid * 37 + i]; m = fmaxf(m, v[i]); }
        float s = 0.f;
        #pragma unroll
        for (int i = 0; i < 37; ++i) { v[i] = expf(v[i] - m); s += v[i]; }
        float inv = 1.f / s;
        #pragma unroll
        for (int i = 0; i < 37; ++i) wop[i * KK + tid] = v[i] * inv;
    } else if (tid < 2 * KK) {
        int r = tid - KK;
        float v[KK + 1];
        float m = -1e30f;
        #pragma unroll
        for (int i = 0; i <= KK; ++i) { v[i] = w_right[r * (KK + 1) + i]; m = fmaxf(m, v[i]); }
        float s = 0.f;
        #pragma unroll
        for (int i = 0; i <= KK; ++i) { v[i] = expf(v[i] - m); s += v[i]; }
        float inv = 1.f / s;
        #pragma unroll
        for (int c = 0; c < KK; ++c) rw[c * KK + r] = v[c] * inv;
    }
}

// --- atom_x = x @ atom_w ; zero state ---
__global__ void atomx_kernel(const float* __restrict__ x, float* __restrict__ ws) {
    const float* aw = ws + WOP_OFF + 5 * KK;
    float* atom  = ws + ATOM_OFF;
    float* state = ws + STATE_OFF;
    int tid = threadIdx.x;
    int k  = tid & (KK - 1);
    int bt = blockIdx.x * 8 + (tid >> 5);
    const float* xrow = x + bt * VV;
    float acc = 0.f;
    #pragma unroll
    for (int v = 0; v < VV; ++v) acc = fmaf(xrow[v], aw[v * KK + k], acc);
    atom[bt * KK + k]  = acc;
    state[bt * KK + k] = 0.f;
}

// --- one phase: MFMA right-product + register/LDS elementwise, PH steps ---
__global__ __launch_bounds__(768, 1)
void phase_kernel(float* __restrict__ ws) {
    __shared__ float  Xf[2][97][XFS];   // fp32 state, dbuf: 27.9 KB
    __shared__ ushort Xb[2][96][XBS];   // bf16 state, dbuf: 15.4 KB

    const float* rw   = ws + RW_OFF;
    const float* wop  = ws + WOP_OFF;
    const float* atom = ws + ATOM_OFF;
    float*      state = ws + STATE_OFF;

    int tid  = threadIdx.x;
    int lane = tid & 63;
    int wave = tid >> 6;
    int b  = blockIdx.x / BPB;
    int c  = blockIdx.x % BPB;
    int lo = c * CH;

    int rtile = wave % 6;          // 6 row-tiles of 16
    int ctile = wave / 6;          // 2 col-tiles of 16
    int lr = lane & 15;
    int hi = lane >> 4;
    int r  = rtile * 16 + lr;      // this lane's state row
    int j0 = ctile * 16 + hi * 4;  // first of 4 owned columns
    int ja = ctile * 16 + lr;      // A-fragment row (j index)

    float* gs = state + (size_t)(b * TT + lo) * KK;

    // stage 96x32 fp32 into both Xf buffers + bf16 into both Xb buffers
    {
        int idx = tid * 4;               // 3072 floats
        int rr = idx >> 5, cc = idx & 31;
        int gt = lo + rr;
        float4 v = make_float4(0.f, 0.f, 0.f, 0.f);
        if (gt < TT) v = *reinterpret_cast<const float4*>(&gs[idx]);
        *reinterpret_cast<float4*>(&Xf[0][rr][cc]) = v;
        *reinterpret_cast<float4*>(&Xf[1][rr][cc]) = v;
        uint2 p;
        p.x = (unsigned int)f2bf(v.x) | ((unsigned int)f2bf(v.y) << 16);
        p.y = (unsigned int)f2bf(v.z) | ((unsigned int)f2bf(v.w) << 16);
        *reinterpret_cast<uint2*>(&Xb[0][rr][cc]) = p;
        *reinterpret_cast<uint2*>(&Xb[1][rr][cc]) = p;
    }
    // zero pads: cols 32..35 rows 0..96 both buffers
    for (int i = tid; i < 97 * 2; i += 768) {
        int bu = i & 1, rr = i >> 1;
        *reinterpret_cast<float4*>(&Xf[bu][rr][32]) = make_float4(0, 0, 0, 0);
    }
    // row 96 cols 0..31 both buffers
    if (tid < 16) {
        int bu = tid & 1, q = tid >> 1;
        *reinterpret_cast<float4*>(&Xf[bu][96][q * 4]) = make_float4(0, 0, 0, 0);
    }

    // per-thread constants
    int gt_r = lo + r;
    float4 av = make_float4(0, 0, 0, 0);
    if (gt_r < TT) av = *reinterpret_cast<const float4*>(&atom[(size_t)(b * TT + gt_r) * KK + j0]);
    float4 w1 = *reinterpret_cast<const float4*>(&wop[1 * KK + j0]);
    float4 w2 = *reinterpret_cast<const float4*>(&wop[2 * KK + j0]);
    float4 w3 = *reinterpret_cast<const float4*>(&wop[3 * KK + j0]);
    float4 w4 = *reinterpret_cast<const float4*>(&wop[4 * KK + j0]);
    float4 c0, d1;
    c0.x = av.x + w1.x - w2.x;  d1.x = w2.x - w1.x;
    c0.y = av.y + w1.y - w2.y;  d1.y = w2.y - w1.y;
    c0.z = av.z + w1.z - w2.z;  d1.z = w2.z - w1.z;
    c0.w = av.w + w1.w - w2.w;  d1.w = w2.w - w1.w;

    // A-fragment: A[j][k] = rw[k*K + j], lane holds row ja, k = hi*8..+7
    short8 afrag;
    #pragma unroll
    for (int q = 0; q < 8; ++q) afrag[q] = (short)f2bf(rw[(hi * 8 + q) * KK + ja]);

    __syncthreads();
    float4 prevf = *reinterpret_cast<const float4*>(&Xf[0][r][j0]);

    int topcap = TT - lo;
    for (int s = 0; s < PH; ++s) {
        int cur = s & 1;
        int top = ROWS - 1 - s; if (top > topcap) top = topcap;
        if (rtile * 16 < top) {
            short8 bfrag = *reinterpret_cast<short8*>(&Xb[cur][r][hi * 8]);
            float4 nx4   = *reinterpret_cast<float4*>(&Xf[cur][r + 1][j0]);
            float  lx0   = Xf[cur][r][j0 + 4];       // left boundary (col j0+4; col32 pad = 0)
            float  lx1   = Xf[cur][r + 1][j0 + 4];   // xl boundary
            floatx4 acc = __builtin_amdgcn_mfma_f32_16x16x32_bf16(
                afrag, bfrag, (floatx4){0.f, 0.f, 0.f, 0.f}, 0, 0, 0);
            float y0, y1, y2, y3;
            {   // q = 0
                float le = prevf.y, nx = nx4.x, xl = nx4.y, rt = acc[0];
                float until = rt + myrelu(le + nx - 1.f);
                float z = c0.x + le * d1.x + rt * w2.x + xl * w3.x + until * w4.x;
                y0 = myrelu(z);
            }
            {   // q = 1
                float le = prevf.z, nx = nx4.y, xl = nx4.z, rt = acc[1];
                float until = rt + myrelu(le + nx - 1.f);
                float z = c0.y + le * d1.y + rt * w2.y + xl * w3.y + until * w4.y;
                y1 = myrelu(z);
            }
            {   // q = 2
                float le = prevf.w, nx = nx4.z, xl = nx4.w, rt = acc[2];
                float until = rt + myrelu(le + nx - 1.f);
                float z = c0.z + le * d1.z + rt * w2.z + xl * w3.z + until * w4.z;
                y2 = myrelu(z);
            }
            {   // q = 3
                float le = lx0, nx = nx4.w, xl = lx1, rt = acc[3];
                float until = rt + myrelu(le + nx - 1.f);
                float z = c0.w + le * d1.w + rt * w2.w + xl * w3.w + until * w4.w;
                y3 = myrelu(z);
            }
            if (r < top) {
                *reinterpret_cast<float4*>(&Xf[cur ^ 1][r][j0]) = make_float4(y0, y1, y2, y3);
                uint2 p;
                p.x = (unsigned int)f2bf(y0) | ((unsigned int)f2bf(y1) << 16);
                p.y = (unsigned int)f2bf(y2) | ((unsigned int)f2bf(y3) << 16);
                *reinterpret_cast<uint2*>(&Xb[cur ^ 1][r][j0]) = p;
                prevf = make_float4(y0, y1, y2, y3);
            }
        }
        __syncthreads();
    }

    // write back chunk rows 0..63 (final state is in buffer 0 after 32 steps)
    if (tid < 512) {
        int idx = tid * 4, rr = idx >> 5, cc = idx & 31;
        *reinterpret_cast<float4*>(&gs[idx]) = *reinterpret_cast<float4*>(&Xf[0][rr][cc]);
    }
}

__global__ void final_kernel(const float* __restrict__ st, float* __restrict__ out) {
    int i = blockIdx.x * 256 + threadIdx.x;
    float v = st[i];
    out[i] = 1.f / (1.f + expf(-5.f * (v - 0.5f)));
}

extern "C" void kernel_launch(void* const* d_in, const int* in_sizes, int n_in,
                              void* d_out, int out_size, void* d_ws, size_t ws_size,
                              hipStream_t stream) {
    const float* x       = (const float*)d_in[0];
    const float* w_right = (const float*)d_in[1];
    const float* w_op    = (const float*)d_in[2];
    float* ws  = (float*)d_ws;
    float* out = (float*)d_out;

    prep_kernel<<<1, 64, 0, stream>>>(w_right, w_op, ws);
    atomx_kernel<<<BB * TT / 8, 256, 0, stream>>>(x, ws);
    for (int p = 0; p < NPHASE; ++p)
        phase_kernel<<<BB * BPB, 768, 0, stream>>>(ws);
    final_kernel<<<BB * TT * KK / 256, 256, 0, stream>>>(ws + STATE_OFF, out);
}

// Round 3
// 201.732 us; speedup vs baseline: 2.0952x; 1.2113x over previous
//
#include <hip/hip_runtime.h>
#include <math.h>

#define BB 64
#define TT 256
#define KK 32
#define VV 32
#define CH 64                    // chunk rows per block
#define PH 32                    // steps per phase
#define ROWS (CH + PH)           // 96 rows covered per block
#define NPHASE ((TT + KK) / PH)  // 9 phases * 32 = 288 steps
#define BPB (TT / CH)            // 4 chunks per batch
#define NW (ROWS / 16)           // 6 waves per block

// workspace layout (floats)
#define RW_OFF    0                       // K*K
#define WOP_OFF   1024                    // 37*K
#define ATOM_OFF  2240                    // B*T*K
#define STATE_OFF (ATOM_OFF + BB*TT*KK)   // B*T*K

typedef __attribute__((ext_vector_type(8))) short short8;
typedef __attribute__((ext_vector_type(4))) float floatx4;

__device__ __forceinline__ float myrelu(float z) {
    // == where(z<0, .01z, where(z>1, .01z+.99, z)) ; med3+mul+fma form
    float c = fminf(fmaxf(z, 0.f), 1.f);
    return fmaf(0.01f, z, 0.99f * c);
}
__device__ __forceinline__ ushort f2bf(float f) {
    union { float f; unsigned int u; } v; v.f = f;
    unsigned int r = v.u + 0x7fffu + ((v.u >> 16) & 1u);
    return (ushort)(r >> 16);
}

// --- softmaxes of w_op (32 x 37) and w_right (32 x 33) ---
__global__ void prep_kernel(const float* __restrict__ w_right,
                            const float* __restrict__ w_op,
                            float* __restrict__ ws) {
    int tid = threadIdx.x;
    float* rw  = ws + RW_OFF;   // rw[k*K + j] = right_w[k][j] = softmax(w_right)[j][k]
    float* wop = ws + WOP_OFF;  // wop[i*K + k] = sm_op[k][i]
    if (tid < KK) {
        float v[37];
        float m = -1e30f;
        #pragma unroll
        for (int i = 0; i < 37; ++i) { v[i] = w_op[tid * 37 + i]; m = fmaxf(m, v[i]); }
        float s = 0.f;
        #pragma unroll
        for (int i = 0; i < 37; ++i) { v[i] = expf(v[i] - m); s += v[i]; }
        float inv = 1.f / s;
        #pragma unroll
        for (int i = 0; i < 37; ++i) wop[i * KK + tid] = v[i] * inv;
    } else if (tid < 2 * KK) {
        int r = tid - KK;
        float v[KK + 1];
        float m = -1e30f;
        #pragma unroll
        for (int i = 0; i <= KK; ++i) { v[i] = w_right[r * (KK + 1) + i]; m = fmaxf(m, v[i]); }
        float s = 0.f;
        #pragma unroll
        for (int i = 0; i <= KK; ++i) { v[i] = expf(v[i] - m); s += v[i]; }
        float inv = 1.f / s;
        #pragma unroll
        for (int c = 0; c < KK; ++c) rw[c * KK + r] = v[c] * inv;
    }
}

// --- atom_x = x @ atom_w ---
__global__ void atomx_kernel(const float* __restrict__ x, float* __restrict__ ws) {
    const float* aw = ws + WOP_OFF + 5 * KK;
    float* atom = ws + ATOM_OFF;
    int tid = threadIdx.x;
    int k  = tid & (KK - 1);
    int bt = blockIdx.x * 8 + (tid >> 5);
    const float* xrow = x + bt * VV;
    float acc = 0.f;
    #pragma unroll
    for (int v = 0; v < VV; ++v) acc = fmaf(xrow[v], aw[v * KK + k], acc);
    atom[bt * KK + k] = acc;
}

// --- one phase: all-register state, MFMA right-product, shfl neighbors ---
__global__ __launch_bounds__(384, 1)
void phase_kernel(float* __restrict__ ws, float* __restrict__ out,
                  int first, int last) {
    __shared__ float brow[2][NW + 1][36];   // tile-boundary rows, dbuf, ~2KB

    const float* rw   = ws + RW_OFF;
    const float* wop  = ws + WOP_OFF;
    const float* atom = ws + ATOM_OFF;
    float*      state = ws + STATE_OFF;

    int tid  = threadIdx.x;
    int lane = tid & 63;
    int rt   = tid >> 6;        // wave = row-tile 0..5
    int lr   = lane & 15;
    int hi   = lane >> 4;
    int b  = blockIdx.x / BPB;
    int c  = blockIdx.x % BPB;
    int lo = c * CH;
    int t0 = lo + rt * 16 + lr;            // this lane's global row
    bool active = (lo + rt * 16) < TT;

    // zero boundary strips (pads cols 32..35 stay 0 forever)
    for (int i = tid; i < 2 * (NW + 1) * 36; i += 384)
        (&brow[0][0][0])[i] = 0.f;

    float* gs = state + (size_t)b * TT * KK;

    float y[8];
    #pragma unroll
    for (int q = 0; q < 8; ++q) y[q] = 0.f;
    if (active && !first) {
        float4 v0 = *reinterpret_cast<const float4*>(&gs[t0 * KK + hi * 8]);
        float4 v1 = *reinterpret_cast<const float4*>(&gs[t0 * KK + hi * 8 + 4]);
        y[0] = v0.x; y[1] = v0.y; y[2] = v0.z; y[3] = v0.w;
        y[4] = v1.x; y[5] = v1.y; y[6] = v1.z; y[7] = v1.w;
    }

    // per-lane constants: cols hi*8..hi*8+7
    float c0[8], d1[8], w2v[8], w3v[8], w4v[8];
    {
        float4 av0 = make_float4(0, 0, 0, 0), av1 = make_float4(0, 0, 0, 0);
        if (active) {
            av0 = *reinterpret_cast<const float4*>(&atom[((size_t)b * TT + t0) * KK + hi * 8]);
            av1 = *reinterpret_cast<const float4*>(&atom[((size_t)b * TT + t0) * KK + hi * 8 + 4]);
        }
        float av[8] = {av0.x, av0.y, av0.z, av0.w, av1.x, av1.y, av1.z, av1.w};
        #pragma unroll
        for (int q = 0; q < 8; ++q) {
            int j = hi * 8 + q;
            float w1 = wop[1 * KK + j];
            float w2 = wop[2 * KK + j];
            c0[q]  = av[q] + w1 - w2;
            d1[q]  = w2 - w1;
            w2v[q] = w2;
            w3v[q] = wop[3 * KK + j];
            w4v[q] = wop[4 * KK + j];
        }
    }

    // A fragments: MFMA0 covers cols col0(m)=(m>>2)*8+(m&3); MFMA1 = +4
    short8 af0, af1;
    {
        int col0 = ((lr >> 2) << 3) | (lr & 3);
        #pragma unroll
        for (int q = 0; q < 8; ++q) {
            af0[q] = (short)f2bf(rw[(hi * 8 + q) * KK + col0]);
            af1[q] = (short)f2bf(rw[(hi * 8 + q) * KK + col0 + 4]);
        }
    }

    __syncthreads();
    if (active && lr == 0) {
        *reinterpret_cast<float4*>(&brow[0][rt][hi * 8])     = make_float4(y[0], y[1], y[2], y[3]);
        *reinterpret_cast<float4*>(&brow[0][rt][hi * 8 + 4]) = make_float4(y[4], y[5], y[6], y[7]);
    }
    __syncthreads();

    for (int s = 0; s < PH; ++s) {
        int cur = s & 1;
        if (active) {
            // pack own row to bf16 B-fragment
            unsigned bw0, bw1, bw2, bw3;
            asm("v_cvt_pk_bf16_f32 %0, %1, %2" : "=v"(bw0) : "v"(y[0]), "v"(y[1]));
            asm("v_cvt_pk_bf16_f32 %0, %1, %2" : "=v"(bw1) : "v"(y[2]), "v"(y[3]));
            asm("v_cvt_pk_bf16_f32 %0, %1, %2" : "=v"(bw2) : "v"(y[4]), "v"(y[5]));
            asm("v_cvt_pk_bf16_f32 %0, %1, %2" : "=v"(bw3) : "v"(y[6]), "v"(y[7]));
            union { unsigned u[4]; short8 v; } bu;
            bu.u[0] = bw0; bu.u[1] = bw1; bu.u[2] = bw2; bu.u[3] = bw3;
            floatx4 acc0 = __builtin_amdgcn_mfma_f32_16x16x32_bf16(
                af0, bu.v, (floatx4){0.f, 0.f, 0.f, 0.f}, 0, 0, 0);
            floatx4 acc1 = __builtin_amdgcn_mfma_f32_16x16x32_bf16(
                af1, bu.v, (floatx4){0.f, 0.f, 0.f, 0.f}, 0, 0, 0);

            // neighbor row r+1 via shfl; tile boundary via LDS strip
            float nx[8];
            #pragma unroll
            for (int q = 0; q < 8; ++q) nx[q] = __shfl(y[q], lane + 1, 64);
            float lb = __shfl(y[0], lane + 16, 64);   // row r,   col hi*8+8
            float xb = __shfl(y[0], lane + 17, 64);   // row r+1, col hi*8+8
            if (lr == 15) {
                float4 n0 = *reinterpret_cast<const float4*>(&brow[cur][rt + 1][hi * 8]);
                float4 n1 = *reinterpret_cast<const float4*>(&brow[cur][rt + 1][hi * 8 + 4]);
                nx[0] = n0.x; nx[1] = n0.y; nx[2] = n0.z; nx[3] = n0.w;
                nx[4] = n1.x; nx[5] = n1.y; nx[6] = n1.z; nx[7] = n1.w;
                xb = brow[cur][rt + 1][hi * 8 + 8];   // pad col 32 == 0 for hi==3
            } else if (hi == 3) {
                xb = 0.f;
            }
            if (hi == 3) lb = 0.f;

            float le[8], xl[8];
            #pragma unroll
            for (int q = 0; q < 7; ++q) { le[q] = y[q + 1]; xl[q] = nx[q + 1]; }
            le[7] = lb; xl[7] = xb;

            #pragma unroll
            for (int q = 0; q < 8; ++q) {
                float rtv = (q < 4) ? acc0[q] : acc1[q - 4];
                float a = le[q] + nx[q] - 1.f;
                float until = rtv + myrelu(a);
                float z = fmaf(until, w4v[q],
                          fmaf(xl[q], w3v[q],
                          fmaf(rtv, w2v[q],
                          fmaf(le[q], d1[q], c0[q]))));
                y[q] = myrelu(z);
            }
        }
        if (active && lr == 0) {
            *reinterpret_cast<float4*>(&brow[cur ^ 1][rt][hi * 8])     = make_float4(y[0], y[1], y[2], y[3]);
            *reinterpret_cast<float4*>(&brow[cur ^ 1][rt][hi * 8 + 4]) = make_float4(y[4], y[5], y[6], y[7]);
        }
        __syncthreads();
    }

    // write back own chunk rows (waves 0..3); halo waves 4,5 don't own rows
    if (rt < CH / 16) {
        if (last) {
            float* op = out + ((size_t)b * TT + t0) * KK + hi * 8;
            float o[8];
            #pragma unroll
            for (int q = 0; q < 8; ++q)
                o[q] = 1.f / (1.f + __expf(-5.f * (y[q] - 0.5f)));
            *reinterpret_cast<float4*>(&op[0]) = make_float4(o[0], o[1], o[2], o[3]);
            *reinterpret_cast<float4*>(&op[4]) = make_float4(o[4], o[5], o[6], o[7]);
        } else {
            *reinterpret_cast<float4*>(&gs[t0 * KK + hi * 8])     = make_float4(y[0], y[1], y[2], y[3]);
            *reinterpret_cast<float4*>(&gs[t0 * KK + hi * 8 + 4]) = make_float4(y[4], y[5], y[6], y[7]);
        }
    }
}

extern "C" void kernel_launch(void* const* d_in, const int* in_sizes, int n_in,
                              void* d_out, int out_size, void* d_ws, size_t ws_size,
                              hipStream_t stream) {
    const float* x       = (const float*)d_in[0];
    const float* w_right = (const float*)d_in[1];
    const float* w_op    = (const float*)d_in[2];
    float* ws  = (float*)d_ws;
    float* out = (float*)d_out;

    prep_kernel<<<1, 64, 0, stream>>>(w_right, w_op, ws);
    atomx_kernel<<<BB * TT / 8, 256, 0, stream>>>(x, ws);
    for (int p = 0; p < NPHASE; ++p)
        phase_kernel<<<BB * BPB, 384, 0, stream>>>(ws, out, p == 0, p == NPHASE - 1);
}

// Round 4
// 184.731 us; speedup vs baseline: 2.2880x; 1.0920x over previous
//
#include <hip/hip_runtime.h>
#include <math.h>

#define BB 64
#define TT 256
#define KK 32
#define VV 32
#define CH 64                    // chunk rows per block
#define PH 32                    // steps per phase
#define ROWS (CH + PH)           // 96 rows covered per block
#define NPHASE ((TT + KK) / PH)  // 9 phases * 32 = 288 steps
#define BPB (TT / CH)            // 4 chunks per batch
#define NW (ROWS / 16)           // 6 waves per block

// workspace layout (floats)
#define RW_OFF    0                       // K*K
#define WOP_OFF   1024                    // 37*K
#define ATOM_OFF  2240                    // B*T*K
#define STATE_OFF (ATOM_OFF + BB*TT*KK)   // B*T*K (halo handoff rows only)
#define FLAG_OFF  (STATE_OFF + BB*TT*KK)  // BB*BPB ints

typedef __attribute__((ext_vector_type(8))) short short8;
typedef __attribute__((ext_vector_type(4))) float floatx4;

__device__ __forceinline__ float myrelu(float z) {
    // 0.01*z + 0.99*clamp(z,0,1)
    return fmaf(0.01f, z, 0.99f * __builtin_amdgcn_fmed3f(z, 0.f, 1.f));
}
__device__ __forceinline__ ushort f2bf(float f) {
    union { float f; unsigned int u; } v; v.f = f;
    unsigned int r = v.u + 0x7fffu + ((v.u >> 16) & 1u);
    return (ushort)(r >> 16);
}
__device__ __forceinline__ float dpp_shl1(float v) {
    // lane n <- lane n+1 within each 16-lane row; top lane of row -> 0
    return __int_as_float(__builtin_amdgcn_update_dpp(
        0, __float_as_int(v), 0x101 /*row_shl:1*/, 0xF, 0xF, true));
}

// --- softmaxes of w_op (32 x 37) and w_right (32 x 33) ---
__global__ void prep_kernel(const float* __restrict__ w_right,
                            const float* __restrict__ w_op,
                            float* __restrict__ ws) {
    int tid = threadIdx.x;
    float* rw  = ws + RW_OFF;   // rw[k*K + j] = right_w[k][j] = softmax(w_right)[j][k]
    float* wop = ws + WOP_OFF;  // wop[i*K + k] = sm_op[k][i]
    if (tid < KK) {
        float v[37];
        float m = -1e30f;
        #pragma unroll
        for (int i = 0; i < 37; ++i) { v[i] = w_op[tid * 37 + i]; m = fmaxf(m, v[i]); }
        float s = 0.f;
        #pragma unroll
        for (int i = 0; i < 37; ++i) { v[i] = expf(v[i] - m); s += v[i]; }
        float inv = 1.f / s;
        #pragma unroll
        for (int i = 0; i < 37; ++i) wop[i * KK + tid] = v[i] * inv;
    } else if (tid < 2 * KK) {
        int r = tid - KK;
        float v[KK + 1];
        float m = -1e30f;
        #pragma unroll
        for (int i = 0; i <= KK; ++i) { v[i] = w_right[r * (KK + 1) + i]; m = fmaxf(m, v[i]); }
        float s = 0.f;
        #pragma unroll
        for (int i = 0; i <= KK; ++i) { v[i] = expf(v[i] - m); s += v[i]; }
        float inv = 1.f / s;
        #pragma unroll
        for (int c = 0; c < KK; ++c) rw[c * KK + r] = v[c] * inv;
    }
}

// --- atom_x = x @ atom_w ; zero the handshake flags ---
__global__ void atomx_kernel(const float* __restrict__ x, float* __restrict__ ws) {
    const float* aw = ws + WOP_OFF + 5 * KK;
    float* atom = ws + ATOM_OFF;
    int tid = threadIdx.x;
    if (blockIdx.x == 0 && tid < BB * BPB) ((int*)(ws + FLAG_OFF))[tid] = 0;
    int k  = tid & (KK - 1);
    int bt = blockIdx.x * 8 + (tid >> 5);
    const float* xrow = x + bt * VV;
    float acc = 0.f;
    #pragma unroll
    for (int v = 0; v < VV; ++v) acc = fmaf(xrow[v], aw[v * KK + k], acc);
    atom[bt * KK + k] = acc;
}

// --- all 288 steps in one cooperative kernel; neighbor-flag phase handoff ---
__global__ __launch_bounds__(384, 1)
void phase_all_kernel(float* __restrict__ ws, float* __restrict__ out) {
    __shared__ float brow[2][NW + 1][36];   // tile-boundary rows, dbuf

    const float* rw   = ws + RW_OFF;
    const float* wop  = ws + WOP_OFF;
    const float* atom = ws + ATOM_OFF;
    float*      state = ws + STATE_OFF;
    int*        flags = (int*)(ws + FLAG_OFF);

    int tid  = threadIdx.x;
    int lane = tid & 63;
    int rt   = tid >> 6;        // wave = row-tile 0..5
    int lr   = lane & 15;
    int hi   = lane >> 4;
    int b  = blockIdx.x / BPB;
    int c  = blockIdx.x % BPB;
    int lo = c * CH;
    int t0 = lo + rt * 16 + lr;            // this lane's global row
    bool active = (lo + rt * 16) < TT;

    for (int i = tid; i < 2 * (NW + 1) * 36; i += 384)
        (&brow[0][0][0])[i] = 0.f;

    float* gs = state + (size_t)b * TT * KK;

    float y[8];
    #pragma unroll
    for (int q = 0; q < 8; ++q) y[q] = 0.f;

    // per-lane constants for cols hi*8..hi*8+7 (folded form):
    // z = acc(c0p + rt*(w2+w4)) + le*d1p + nx*w4n + med3(le+nx,1,2)*w4c + xl*w3
    float c0p[8], d1p[8], w3v[8], w4n[8], w4c[8];
    {
        float av[8] = {0, 0, 0, 0, 0, 0, 0, 0};
        if (active) {
            float4 a0 = *reinterpret_cast<const float4*>(&atom[((size_t)b * TT + t0) * KK + hi * 8]);
            float4 a1 = *reinterpret_cast<const float4*>(&atom[((size_t)b * TT + t0) * KK + hi * 8 + 4]);
            av[0] = a0.x; av[1] = a0.y; av[2] = a0.z; av[3] = a0.w;
            av[4] = a1.x; av[5] = a1.y; av[6] = a1.z; av[7] = a1.w;
        }
        #pragma unroll
        for (int q = 0; q < 8; ++q) {
            int j = hi * 8 + q;
            float w1 = wop[1 * KK + j];
            float w2 = wop[2 * KK + j];
            float w3 = wop[3 * KK + j];
            float w4 = wop[4 * KK + j];
            c0p[q] = av[q] + w1 - w2 - w4;
            d1p[q] = (w2 - w1) + 0.01f * w4;
            w4n[q] = 0.01f * w4;
            w4c[q] = 0.99f * w4;
            w3v[q] = w3;
        }
    }

    // A fragments scaled by (w2+w4) per output column; col0(m)=(m>>2)*8+(m&3)
    short8 af0, af1;
    {
        int col0 = ((lr >> 2) << 3) | (lr & 3);
        float s0 = wop[2 * KK + col0]     + wop[4 * KK + col0];
        float s1 = wop[2 * KK + col0 + 4] + wop[4 * KK + col0 + 4];
        #pragma unroll
        for (int q = 0; q < 8; ++q) {
            af0[q] = (short)f2bf(rw[(hi * 8 + q) * KK + col0] * s0);
            af1[q] = (short)f2bf(rw[(hi * 8 + q) * KK + col0 + 4] * s1);
        }
    }

    int pidx = ((lane + 16) & 63) << 2;   // bpermute byte addr for lane+16
    __syncthreads();

    for (int p = 0; p < NPHASE; ++p) {
        for (int s = 0; s < PH; ++s) {
            int cur = s & 1;
            if (active) {
                unsigned bw0, bw1, bw2, bw3;
                asm("v_cvt_pk_bf16_f32 %0, %1, %2" : "=v"(bw0) : "v"(y[0]), "v"(y[1]));
                asm("v_cvt_pk_bf16_f32 %0, %1, %2" : "=v"(bw1) : "v"(y[2]), "v"(y[3]));
                asm("v_cvt_pk_bf16_f32 %0, %1, %2" : "=v"(bw2) : "v"(y[4]), "v"(y[5]));
                asm("v_cvt_pk_bf16_f32 %0, %1, %2" : "=v"(bw3) : "v"(y[6]), "v"(y[7]));
                union { unsigned u[4]; short8 v; } bu;
                bu.u[0] = bw0; bu.u[1] = bw1; bu.u[2] = bw2; bu.u[3] = bw3;
                floatx4 acc0 = __builtin_amdgcn_mfma_f32_16x16x32_bf16(
                    af0, bu.v, (floatx4){c0p[0], c0p[1], c0p[2], c0p[3]}, 0, 0, 0);
                floatx4 acc1 = __builtin_amdgcn_mfma_f32_16x16x32_bf16(
                    af1, bu.v, (floatx4){c0p[4], c0p[5], c0p[6], c0p[7]}, 0, 0, 0);

                // neighbor row r+1 via DPP; 16-row tile boundary via LDS strip
                float nx[8];
                #pragma unroll
                for (int q = 0; q < 8; ++q) nx[q] = dpp_shl1(y[q]);
                float lbr = __int_as_float(__builtin_amdgcn_ds_bpermute(pidx, __float_as_int(y[0])));
                float lb  = (hi == 3) ? 0.f : lbr;    // row r, col hi*8+8
                float xb  = dpp_shl1(lb);             // row r+1, col hi*8+8
                if (hi == 3) xb = 0.f;
                if (lr == 15) {
                    float4 n0 = *reinterpret_cast<const float4*>(&brow[cur][rt + 1][hi * 8]);
                    float4 n1 = *reinterpret_cast<const float4*>(&brow[cur][rt + 1][hi * 8 + 4]);
                    nx[0] = n0.x; nx[1] = n0.y; nx[2] = n0.z; nx[3] = n0.w;
                    nx[4] = n1.x; nx[5] = n1.y; nx[6] = n1.z; nx[7] = n1.w;
                    xb = brow[cur][rt + 1][hi * 8 + 8];   // pad col 32 == 0 for hi==3
                }

                float le[8], xl[8];
                #pragma unroll
                for (int q = 0; q < 7; ++q) { le[q] = y[q + 1]; xl[q] = nx[q + 1]; }
                le[7] = lb; xl[7] = xb;

                #pragma unroll
                for (int q = 0; q < 8; ++q) {
                    float accq = (q < 4) ? acc0[q] : acc1[q - 4];
                    float sm = le[q] + nx[q];
                    float t  = __builtin_amdgcn_fmed3f(sm, 1.f, 2.f);
                    float z  = fmaf(le[q], d1p[q],
                               fmaf(nx[q], w4n[q],
                               fmaf(t, w4c[q],
                               fmaf(xl[q], w3v[q], accq))));
                    y[q] = myrelu(z);
                }
                if (lr == 0) {
                    *reinterpret_cast<float4*>(&brow[cur ^ 1][rt][hi * 8])     = make_float4(y[0], y[1], y[2], y[3]);
                    *reinterpret_cast<float4*>(&brow[cur ^ 1][rt][hi * 8 + 4]) = make_float4(y[4], y[5], y[6], y[7]);
                }
            }
            __syncthreads();
        }
        if (p == NPHASE - 1) break;

        // ---- phase boundary: publish rows 0..31 to left neighbor; reload halo ----
        if (rt < 2 && c > 0) {
            unsigned long long* gp =
                reinterpret_cast<unsigned long long*>(gs + (size_t)t0 * KK + hi * 8);
            union { float f[8]; unsigned long long u[4]; } pk;
            #pragma unroll
            for (int q = 0; q < 8; ++q) pk.f[q] = y[q];
            #pragma unroll
            for (int w = 0; w < 4; ++w)
                __hip_atomic_store(&gp[w], pk.u[w], __ATOMIC_RELAXED, __HIP_MEMORY_SCOPE_AGENT);
        }
        __syncthreads();
        if (tid == 0) {
            if (c > 0)
                __hip_atomic_store(&flags[b * BPB + c], p + 1,
                                   __ATOMIC_RELEASE, __HIP_MEMORY_SCOPE_AGENT);
            if (c < BPB - 1) {
                while (__hip_atomic_load(&flags[b * BPB + c + 1],
                                         __ATOMIC_ACQUIRE, __HIP_MEMORY_SCOPE_AGENT) < p + 1)
                    __builtin_amdgcn_s_sleep(2);
            }
        }
        __syncthreads();
        if (active && rt >= CH / 16) {      // halo waves 4,5 reload fresh rows
            unsigned long long* gp =
                reinterpret_cast<unsigned long long*>(gs + (size_t)t0 * KK + hi * 8);
            union { float f[8]; unsigned long long u[4]; } pk;
            #pragma unroll
            for (int w = 0; w < 4; ++w)
                pk.u[w] = __hip_atomic_load(&gp[w], __ATOMIC_RELAXED, __HIP_MEMORY_SCOPE_AGENT);
            #pragma unroll
            for (int q = 0; q < 8; ++q) y[q] = pk.f[q];
            if (lr == 0) {
                *reinterpret_cast<float4*>(&brow[0][rt][hi * 8])     = make_float4(y[0], y[1], y[2], y[3]);
                *reinterpret_cast<float4*>(&brow[0][rt][hi * 8 + 4]) = make_float4(y[4], y[5], y[6], y[7]);
            }
        }
        __syncthreads();
    }

    // epilogue: sigmoid + store (chunk waves 0..3 only)
    if (rt < CH / 16) {
        float* op = out + ((size_t)b * TT + t0) * KK + hi * 8;
        float o[8];
        #pragma unroll
        for (int q = 0; q < 8; ++q)
            o[q] = 1.f / (1.f + __expf(-5.f * (y[q] - 0.5f)));
        *reinterpret_cast<float4*>(&op[0]) = make_float4(o[0], o[1], o[2], o[3]);
        *reinterpret_cast<float4*>(&op[4]) = make_float4(o[4], o[5], o[6], o[7]);
    }
}

extern "C" void kernel_launch(void* const* d_in, const int* in_sizes, int n_in,
                              void* d_out, int out_size, void* d_ws, size_t ws_size,
                              hipStream_t stream) {
    const float* x       = (const float*)d_in[0];
    const float* w_right = (const float*)d_in[1];
    const float* w_op    = (const float*)d_in[2];
    float* ws  = (float*)d_ws;
    float* out = (float*)d_out;

    prep_kernel<<<1, 64, 0, stream>>>(w_right, w_op, ws);
    atomx_kernel<<<BB * TT / 8, 256, 0, stream>>>(x, ws);

    void* args[] = { (void*)&ws, (void*)&out };
    hipLaunchCooperativeKernel((void*)phase_all_kernel,
                               dim3(BB * BPB), dim3(384), args, 0, stream);
}